// Round 15
// baseline (178.957 us; speedup 1.0000x reference)
//
#include <hip/hip_runtime.h>
#include <math.h>

#define DECAY 0.8f
constexpr int B_     = 16;
constexpr int NSEQ   = 4096;
constexpr int D      = 64;
constexpr int C      = 4096;
constexpr int N      = B_ * NSEQ;       // 65536 rows
constexpr int NCHUNK = 4;               // code chunks (blockIdx.y)
constexpr int CCHUNK = C / NCHUNK;      // 1024 codes
constexpr int PANEL  = 128;             // codes per panel (32 KB LDS)
constexpr int NPANEL = CCHUNK / PANEL;  // 8
constexpr int TILE_ELEMS = 32 * D;      // 2048 elems per 32-code tile image

#define GATE_THR  3e-4f                  // > 2x mfma-split err (~1e-4 bound)

typedef __attribute__((ext_vector_type(8)))  short bf16x8;
typedef __attribute__((ext_vector_type(16))) float f32x16;

__device__ __forceinline__ unsigned short bf16_rn(float f) {
    unsigned u = __builtin_bit_cast(unsigned, f);
    u += 0x7FFFu + ((u >> 16) & 1u);
    return (unsigned short)(u >> 16);
}
__device__ __forceinline__ float bf16_to_f(unsigned short h) {
    unsigned u = ((unsigned)h) << 16;
    return __builtin_bit_cast(float, u);
}
__device__ __forceinline__ f32x16 mfma32(bf16x8 a, bf16x8 b, f32x16 c) {
    return __builtin_amdgcn_mfma_f32_32x32x16_bf16(a, b, c, 0, 0, 0);
}
__device__ __forceinline__ void gload_lds16(const unsigned short* g,
                                            unsigned short* l) {
    __builtin_amdgcn_global_load_lds(
        (const __attribute__((address_space(1))) unsigned int*)g,
        (__attribute__((address_space(3))) unsigned int*)l, 16, 0, 0);
}

// ---------------------------------------------------------------------------
// Kernel 1: embed_n = l2norm(embed) (f32), bf16 hi/lo split in the
// TRANSPOSED-GRANULE tile image (t*2048 + (g*32+r)*8 + e). Zeroes ncpy
// copies of embed_sum/bins + dirty_count.
// ---------------------------------------------------------------------------
__global__ __launch_bounds__(256) void prep_e_kernel(
    const float* __restrict__ embed,
    float* __restrict__ embed_n,
    unsigned short* __restrict__ e_hi,
    unsigned short* __restrict__ e_lo,
    float* __restrict__ embed_sum,
    float* __restrict__ bins,
    int* __restrict__ dirty_count,
    int ncpy)
{
    int code = blockIdx.x * 4 + (threadIdx.x >> 6);
    int lane = threadIdx.x & 63;
    float v = embed[code * D + lane];
    float ss = v * v;
    #pragma unroll
    for (int o = 32; o > 0; o >>= 1) ss += __shfl_xor(ss, o);
    float inv = 1.0f / fmaxf(sqrtf(ss), 1e-12f);
    float en = v * inv;
    embed_n[code * D + lane] = en;

    unsigned short hi = bf16_rn(en);
    unsigned short lo = bf16_rn(en - bf16_to_f(hi));
    int t = code >> 5, r = code & 31;
    int g = lane >> 3, e = lane & 7;
    size_t pos = (size_t)t * TILE_ELEMS + (g * 32 + r) * 8 + e;
    e_hi[pos] = hi;
    e_lo[pos] = lo;

    for (int k = 0; k < ncpy; ++k) {
        embed_sum[(size_t)k * C * D + code * D + lane] = 0.0f;
        if (lane == 0) bins[k * C + code] = 0.0f;
    }
    if (blockIdx.x == 0 && threadIdx.x == 0) *dirty_count = 0;
}

// ---------------------------------------------------------------------------
// Kernel 2: MFMA partial argmax over a 1024-code chunk (blockIdx.y of 4).
// 64 ROWS PER WAVE (2 row-groups of 32): one eh/el LDS read now feeds 6
// MFMAs instead of 3 — total ds_read_b128 traffic halves (was co-equal with
// the 41 µs MFMA floor per round-14 accounting). 512 blocks = 2/CU x 8
// waves; VGPR ~120 -> 4 waves/SIMD (16 waves/CU).
// Single 12-MFMA chain per row-group; the two groups interleave for ILP
// (round-11 lesson) and the accA+accB adds disappear (VALU -20%).
// Exact elementwise top-2 + index per row-group (round-14 verified, absmax
// 0): cit(r) inline const, pt SGPR; exact ties -> m2==m1 -> dirty.
// Partial (m1, exact code, exact m2, 0) -> row's quantize slot (f4 @chunk*4).
// ---------------------------------------------------------------------------
__global__ __launch_bounds__(512) void assign_mfma_kernel(
    const float* __restrict__ x,
    const unsigned short* __restrict__ e_hi,
    const unsigned short* __restrict__ e_lo,
    float* __restrict__ part)               // == q_out region of d_out
{
    __shared__ unsigned short lds_hi[4 * TILE_ELEMS];   // 16 KB
    __shared__ unsigned short lds_lo[4 * TILE_ELEMS];   // 16 KB

    const int tid  = threadIdx.x;
    const int lane = tid & 63;
    const int wid  = tid >> 6;                   // 0..7
    const int m    = lane & 31;
    const int hi   = lane >> 5;                  // 0/1
    const int rb   = (blockIdx.x * 8 + wid) * 64;    // 64 rows per wave
    const int cy   = blockIdx.y;                 // code chunk 0..3

    // ---- x fragments for BOTH row-groups: 4 K-chunks of 16, bf16 hi/lo
    bf16x8 xhi[2][4], xlo[2][4];
    #pragma unroll
    for (int g = 0; g < 2; ++g) {
        #pragma unroll
        for (int c = 0; c < 4; ++c) {
            const float* p = x + (size_t)(rb + g * 32 + m) * D + c * 16 + hi * 8;
            float4 t0 = *(const float4*)p;
            float4 t1 = *(const float4*)(p + 4);
            float e[8] = {t0.x, t0.y, t0.z, t0.w, t1.x, t1.y, t1.z, t1.w};
            bf16x8 h, l2;
            #pragma unroll
            for (int j = 0; j < 8; ++j) {
                unsigned short hh = bf16_rn(e[j]);
                h[j]  = (short)hh;
                l2[j] = (short)bf16_rn(e[j] - bf16_to_f(hh));
            }
            xhi[g][c] = h;
            xlo[g][c] = l2;
        }
    }

    float m1[2] = {-3.4e38f, -3.4e38f};
    float m2[2] = {-3.4e38f, -3.4e38f};
    int   tl[2] = {0, 0}, il[2] = {0, 0};

    for (int p = 0; p < NPANEL; ++p) {           // 8 panels of 128 codes
        const size_t pbase = ((size_t)cy * NPANEL + p) * (4 * TILE_ELEMS);
        __syncthreads();
        gload_lds16(e_hi + pbase + tid * 8,        &lds_hi[tid * 8]);
        gload_lds16(e_hi + pbase + 4096 + tid * 8, &lds_hi[4096 + tid * 8]);
        gload_lds16(e_lo + pbase + tid * 8,        &lds_lo[tid * 8]);
        gload_lds16(e_lo + pbase + 4096 + tid * 8, &lds_lo[4096 + tid * 8]);
        __syncthreads();

        #pragma unroll
        for (int t = 0; t < 4; ++t) {            // 4 code-tiles of 32
            const int pt = (cy * NPANEL + p) * 4 + t;    // tile id 0..127
            f32x16 acc0 = {}, acc1 = {};         // one chain per row-group
            #pragma unroll
            for (int c = 0; c < 4; ++c) {
                const int off = t * TILE_ELEMS + ((c * 2 + hi) * 32 + m) * 8;
                bf16x8 eh = *(const bf16x8*)(lds_hi + off);
                bf16x8 el = *(const bf16x8*)(lds_lo + off);
                acc0 = mfma32(eh, xhi[0][c], acc0);   // groups interleave = ILP
                acc1 = mfma32(eh, xhi[1][c], acc1);
                acc0 = mfma32(el, xhi[0][c], acc0);
                acc1 = mfma32(el, xhi[1][c], acc1);
                acc0 = mfma32(eh, xlo[0][c], acc0);
                acc1 = mfma32(eh, xlo[1][c], acc1);
            }
            // exact elementwise top-2 + index, per row-group
            #pragma unroll
            for (int r = 0; r < 16; ++r) {
                const int cit = (r & 3) + 8 * (r >> 2);  // inline const
                {
                    float v = acc0[r];
                    bool gt = v > m1[0];
                    float mx = fmaxf(m2[0], v);
                    m2[0] = gt ? m1[0] : mx;
                    tl[0] = gt ? pt : tl[0];
                    il[0] = gt ? cit : il[0];
                    m1[0] = fmaxf(m1[0], v);
                }
                {
                    float v = acc1[r];
                    bool gt = v > m1[1];
                    float mx = fmaxf(m2[1], v);
                    m2[1] = gt ? m1[1] : mx;
                    tl[1] = gt ? pt : tl[1];
                    il[1] = gt ? cit : il[1];
                    m1[1] = fmaxf(m1[1], v);
                }
            }
        }
    }

    // ---- per group: global code; merge hi-halves; write partial
    #pragma unroll
    for (int g = 0; g < 2; ++g) {
        int code = (tl[g] << 5) + il[g] + (hi << 2);
        float a1 = m1[g], a2 = m2[g];
        {
            float b1 = __shfl_xor(a1, 32);
            float b2 = __shfl_xor(a2, 32);
            int   bc = __shfl_xor(code, 32);
            float nm2 = fmaxf(fmaxf(a2, b2), fminf(a1, b1));
            bool  take = (b1 > a1) || (b1 == a1 && bc < code);
            a1   = take ? b1 : a1;
            code = take ? bc : code;
            a2   = nm2;
        }
        if (lane < 32) {
            int row = rb + g * 32 + lane;
            float4 pr;
            pr.x = a1; pr.y = (float)code; pr.z = a2; pr.w = 0.0f;
            *reinterpret_cast<float4*>(part + (size_t)row * D + cy * 4) = pr;
        }
    }
}

// ---------------------------------------------------------------------------
// Kernel 3: merge + scatter, one WAVE per row (round-14 verified, absmax 0).
// Winner = compare of 4 exact chunk partials; gate m1-m2x <= GATE_THR.
// Clean rows: ind + bins + q gather + embed_sum atomics (privatized ncpy).
// ---------------------------------------------------------------------------
__global__ __launch_bounds__(256) void merge_scatter_kernel(
    const float* __restrict__ x,
    const float* __restrict__ embed,
    float* __restrict__ q_out,               // holds partials on entry
    float* __restrict__ ind_out,
    float* __restrict__ embed_sum,
    float* __restrict__ bins,
    int* __restrict__ dirty_count,
    int* __restrict__ dirty_list,
    int ncpy)
{
    int wid  = threadIdx.x >> 6;
    int lane = threadIdx.x & 63;
    int row  = blockIdx.x * 4 + wid;
    int cpy  = blockIdx.x & (ncpy - 1);

    float w1, m2x; int wc;
    {
        const float4* pp = reinterpret_cast<const float4*>(q_out + (size_t)row * D);
        float4 P = pp[0];
        w1 = P.x; wc = (int)P.y; m2x = P.z;
        #pragma unroll
        for (int j = 1; j < NCHUNK; ++j) {
            float4 Q = pp[j];
            float nm2 = fmaxf(fmaxf(m2x, Q.z), fminf(w1, Q.x));
            if (Q.x > w1) { w1 = Q.x; wc = (int)Q.y; }
            m2x = nm2;
        }
    }

    bool dirty = (w1 - m2x <= GATE_THR);
    if (dirty) {
        if (lane == 0) {
            int slot = atomicAdd(dirty_count, 1);
            dirty_list[slot] = row;
        }
        return;
    }

    float xk = x[(size_t)row * D + lane];
    float ss = xk * xk;
    #pragma unroll
    for (int o = 32; o > 0; o >>= 1) ss += __shfl_xor(ss, o);
    float inv = 1.0f / fmaxf(sqrtf(ss), 1e-12f);

    if (lane == 0) {
        ind_out[row] = (float)wc;
        atomicAdd(&bins[cpy * C + wc], 1.0f);
    }
    q_out[(size_t)row * D + lane] = embed[(size_t)wc * D + lane];
    atomicAdd(&embed_sum[(size_t)cpy * C * D + (size_t)wc * D + lane], xk * inv);
}

// ---------------------------------------------------------------------------
// Kernel 4: exact fp32 re-argmax for dirty rows + their deferred scatter.
// ---------------------------------------------------------------------------
__global__ __launch_bounds__(256) void fallback_kernel(
    const float* __restrict__ x,
    const float* __restrict__ embed,
    const float* __restrict__ embed_n,
    const int* __restrict__ dirty_count,
    const int* __restrict__ dirty_list,
    float* __restrict__ ind_out,
    float* __restrict__ q_out,
    float* __restrict__ embed_sum,
    float* __restrict__ bins,
    int ncpy)
{
    __shared__ float xs[D];
    __shared__ float bv[256];
    __shared__ int   bidx[256];
    int cnt = *dirty_count;
    int cpy = blockIdx.x & (ncpy - 1);
    for (int i = blockIdx.x; i < cnt; i += gridDim.x) {
        int row = dirty_list[i];
        __syncthreads();
        if (threadIdx.x < D) xs[threadIdx.x] = x[(size_t)row * D + threadIdx.x];
        __syncthreads();
        float best = -3.4e38f;
        int   bi   = 0;
        int   c0   = threadIdx.x * 16;
        for (int c = c0; c < c0 + 16; ++c) {
            const float4* ep = (const float4*)(embed_n + (size_t)c * D);
            const float4* xp = (const float4*)xs;
            float a0 = 0.f, a1 = 0.f, a2 = 0.f, a3 = 0.f;
            #pragma unroll
            for (int k = 0; k < D / 4; ++k) {
                float4 e = ep[k], xx = xp[k];
                a0 = fmaf(e.x, xx.x, a0);
                a1 = fmaf(e.y, xx.y, a1);
                a2 = fmaf(e.z, xx.z, a2);
                a3 = fmaf(e.w, xx.w, a3);
            }
            float dd = (a0 + a1) + (a2 + a3);
            if (dd > best) { best = dd; bi = c; }
        }
        bv[threadIdx.x]   = best;
        bidx[threadIdx.x] = bi;
        __syncthreads();
        #pragma unroll
        for (int s = 128; s > 0; s >>= 1) {
            if (threadIdx.x < s) {
                float v2 = bv[threadIdx.x + s];
                int   i2 = bidx[threadIdx.x + s];
                if (v2 > bv[threadIdx.x] ||
                    (v2 == bv[threadIdx.x] && i2 < bidx[threadIdx.x])) {
                    bv[threadIdx.x]   = v2;
                    bidx[threadIdx.x] = i2;
                }
            }
            __syncthreads();
        }
        int fi = bidx[0];
        if (threadIdx.x == 0) {
            ind_out[row] = (float)fi;
            atomicAdd(&bins[cpy * C + fi], 1.0f);
        }
        if (threadIdx.x < 64) {
            float xk = xs[threadIdx.x];
            float ss = xk * xk;
            #pragma unroll
            for (int o = 32; o > 0; o >>= 1) ss += __shfl_xor(ss, o);
            float inv = 1.0f / fmaxf(sqrtf(ss), 1e-12f);
            q_out[(size_t)row * D + threadIdx.x] =
                embed[(size_t)fi * D + threadIdx.x];
            atomicAdd(&embed_sum[(size_t)cpy * C * D + (size_t)fi * D + threadIdx.x],
                      xk * inv);
        }
        __syncthreads();
    }
}

// ---------------------------------------------------------------------------
// Kernel 5: EMA finalize per code. One wave per code; sums the ncpy copies.
// ---------------------------------------------------------------------------
__global__ __launch_bounds__(256) void finalize_kernel(
    const float* __restrict__ embed,
    const float* __restrict__ cluster_size,
    const float* __restrict__ embed_n,
    const float* __restrict__ embed_sum,
    const float* __restrict__ bins,
    float* __restrict__ new_embed_out,
    float* __restrict__ new_cs_out,
    int ncpy)
{
    int code = blockIdx.x * 4 + (threadIdx.x >> 6);
    int lane = threadIdx.x & 63;
    float bsum = 0.0f;
    for (int k = 0; k < ncpy; ++k) bsum += bins[k * C + code];
    if (lane == 0)
        new_cs_out[code] = cluster_size[code] * DECAY + bsum * (1.0f - DECAY);

    float en;
    if (bsum == 0.0f) {
        en = embed_n[code * D + lane];
    } else {
        float vsum = 0.0f;
        for (int k = 0; k < ncpy; ++k)
            vsum += embed_sum[(size_t)k * C * D + code * D + lane];
        float v = vsum / bsum;
        float ss = v * v;
        #pragma unroll
        for (int o = 32; o > 0; o >>= 1) ss += __shfl_xor(ss, o);
        en = v / fmaxf(sqrtf(ss), 1e-12f);
    }
    new_embed_out[code * D + lane] =
        embed[code * D + lane] * DECAY + en * (1.0f - DECAY);
}

// ---------------------------------------------------------------------------
extern "C" void kernel_launch(void* const* d_in, const int* in_sizes, int n_in,
                              void* d_out, int out_size, void* d_ws, size_t ws_size,
                              hipStream_t stream)
{
    const float* x            = (const float*)d_in[0];
    const float* embed        = (const float*)d_in[1];
    const float* cluster_size = (const float*)d_in[2];

    float* out     = (float*)d_out;
    float* q_out   = out;                          // N*D
    float* ind_out = out + (size_t)N * D;          // N
    float* ne_out  = ind_out + N;                  // C*D
    float* ncs_out = ne_out + (size_t)C * D;       // C

    // ws layout (bytes):
    //   embed_n     @ 0        (1 MB)
    //   e_hi        @ 1 MB     (512 KB)
    //   e_lo        @ 1.5 MB   (512 KB)
    //   bins        @ 2 MB     (ncpy * 16 KB, ncpy<=4)
    //   dirty_list  @ 2.25 MB  (256 KB)
    //   dirty_count @ 2.5 MB   (4 B)
    //   embed_sum   @ 3 MB     (ncpy * 1 MB)
    char* ws = (char*)d_ws;
    float*          embed_n     = (float*)ws;
    unsigned short* e_hi        = (unsigned short*)(ws + (1u << 20));
    unsigned short* e_lo        = (unsigned short*)(ws + (1u << 20) + 524288);
    float*          bins        = (float*)(ws + (2u << 20));
    int*            dirty_list  = (int*)(ws + (2u << 20) + 262144);
    int*            dirty_count = (int*)(ws + (2u << 20) + 524288);
    float*          embed_sum   = (float*)(ws + (3u << 20));

    const size_t need4 = (3u << 20) + 4u * ((size_t)C * D * 4);
    const int ncpy = (ws_size >= need4) ? 4 : 1;   // privatization degree

    prep_e_kernel<<<C / 4, 256, 0, stream>>>(embed, embed_n, e_hi, e_lo,
                                             embed_sum, bins, dirty_count, ncpy);
    assign_mfma_kernel<<<dim3(N / 512, NCHUNK), 512, 0, stream>>>(
        x, e_hi, e_lo, q_out);
    merge_scatter_kernel<<<N / 4, 256, 0, stream>>>(x, embed, q_out, ind_out,
                                                    embed_sum, bins,
                                                    dirty_count, dirty_list, ncpy);
    fallback_kernel<<<1024, 256, 0, stream>>>(x, embed, embed_n, dirty_count,
                                              dirty_list, ind_out, q_out,
                                              embed_sum, bins, ncpy);
    finalize_kernel<<<C / 4, 256, 0, stream>>>(embed, cluster_size, embed_n,
                                               embed_sum, bins, ne_out, ncs_out,
                                               ncpy);
}